// Round 1
// baseline (441.940 us; speedup 1.0000x reference)
//
#include <hip/hip_runtime.h>
#include <hip/hip_bf16.h>

typedef __bf16 bf16;
typedef __bf16 bf16x8 __attribute__((ext_vector_type(8)));
typedef __bf16 bf16x4 __attribute__((ext_vector_type(4)));
typedef float f32x4 __attribute__((ext_vector_type(4)));

static __device__ __forceinline__ f32x4 mfma16(bf16x8 a, bf16x8 b, f32x4 c) {
    return __builtin_amdgcn_mfma_f32_16x16x32_bf16(a, b, c, 0, 0, 0);
}

// ---------------- convert f32 -> bf16 (vectorized x4) ----------------
__global__ void convert_f32_bf16(const float* __restrict__ src, bf16* __restrict__ dst, int n4) {
    int i = blockIdx.x * blockDim.x + threadIdx.x;
    if (i < n4) {
        float4 v = *(const float4*)(src + (size_t)i * 4);
        bf16x4 o;
        o[0] = (bf16)v.x; o[1] = (bf16)v.y; o[2] = (bf16)v.z; o[3] = (bf16)v.w;
        *(bf16x4*)(dst + (size_t)i * 4) = o;
    }
}

// ---------------- GEMM: Y[M x 256] = X[M x 256] (f32) * W^T (bf16 [256][256]) ----------------
// scale applied to accumulator; optional bias; output bf16 or f32.
// grid.x = M/64, block = 256 (4 waves, each 16 rows x 256 cols)
template<bool OUT_BF16, bool HAS_BIAS>
__global__ __launch_bounds__(256) void gemm256(const float* __restrict__ X,
                                               const bf16* __restrict__ W,
                                               const float* __restrict__ bias,
                                               float scale,
                                               void* __restrict__ Y) {
    __shared__ __align__(16) bf16 Xl[64][264];   // +8 pad -> 2-way banks on a-frag reads
    __shared__ __align__(16) bf16 Wl[256][40];   // 32 k + 8 pad
    const int tid  = threadIdx.x;
    const int lane = tid & 63, wave = tid >> 6;
    const int hi = lane >> 4, lo = lane & 15;
    const long rowbase = (long)blockIdx.x * 64;

    // stage X tile [64][256] f32 -> bf16 (coalesced float4 reads)
#pragma unroll
    for (int i = 0; i < 16; ++i) {
        int idx4 = i * 256 + tid;          // 4096 groups of 4 elements
        int e = idx4 * 4;
        int r = e >> 8, c = e & 255;
        float4 v = *(const float4*)(X + (rowbase + r) * 256 + c);
        bf16x4 o;
        o[0] = (bf16)v.x; o[1] = (bf16)v.y; o[2] = (bf16)v.z; o[3] = (bf16)v.w;
        *(bf16x4*)(&Xl[r][c]) = o;
    }

    f32x4 acc[16];
    const f32x4 zero = {0.f, 0.f, 0.f, 0.f};
#pragma unroll
    for (int n = 0; n < 16; ++n) acc[n] = zero;

    for (int ks = 0; ks < 8; ++ks) {
        __syncthreads();   // protects Wl (prev reads done) and, first time, Xl visibility ordering below
        // stage W tile: W[e][ks*32 .. +31] -> Wl[e][0..31]
#pragma unroll
        for (int c = 0; c < 4; ++c) {
            int idx = c * 256 + tid;       // 1024 chunks of 16B
            int e = idx >> 2, part = idx & 3;
            uint4 v = *(const uint4*)((const char*)W + (size_t)e * 512 + ks * 64 + part * 16);
            *(uint4*)((char*)&Wl[0][0] + e * 80 + part * 16) = v;
        }
        __syncthreads();
        bf16x8 a = *(const bf16x8*)((const char*)&Xl[0][0] + (wave * 16 + lo) * 528 + ks * 64 + hi * 16);
#pragma unroll
        for (int n = 0; n < 16; ++n) {
            bf16x8 bfr = *(const bf16x8*)((const char*)&Wl[0][0] + (n * 16 + lo) * 80 + hi * 16);
            acc[n] = mfma16(a, bfr, acc[n]);
        }
    }

    // epilogue: C layout col=lane&15, row=(lane>>4)*4+reg  [verified m89]
#pragma unroll
    for (int n = 0; n < 16; ++n) {
        int col = n * 16 + lo;
        float bv = HAS_BIAS ? bias[col] : 0.f;
#pragma unroll
        for (int r = 0; r < 4; ++r) {
            long row = rowbase + wave * 16 + hi * 4 + r;
            float v = acc[n][r] * scale + bv;
            if (OUT_BF16) ((bf16*)Y)[row * 256 + col] = (bf16)v;
            else          ((float*)Y)[row * 256 + col] = v;
        }
    }
}

// ---------------- flash attention + gate ----------------
// grid = (LQ/64, B), block = 256 (4 waves, 16 q-rows each). KV tiles of 32.
__global__ __launch_bounds__(256) void flash_kernel(const bf16* __restrict__ qp,
                                                    const bf16* __restrict__ kp,
                                                    const bf16* __restrict__ tspb,
                                                    const float* __restrict__ qorig,
                                                    float* __restrict__ gated) {
    __shared__ __align__(16) char kp_lds[32 * 512];      // [kv][512B], XOR-swizzled
    __shared__ __align__(16) bf16 tspT[256][40];         // [d][kv], +8 pad
    __shared__ __align__(16) bf16 p_lds[4][16][40];      // per-wave P, +8 pad
    const int tid  = threadIdx.x;
    const int lane = tid & 63, wave = tid >> 6;
    const int hi = lane >> 4, lo = lane & 15;
    const int b = blockIdx.y;
    const long qbase_g = (long)b * 2048 + (long)blockIdx.x * 64;

    // qp fragments for this wave's 16 rows (row = lane&15), full K=256
    bf16x8 aq[8];
    {
        const bf16* qrowp = qp + (qbase_g + wave * 16 + lo) * 256;
#pragma unroll
        for (int ks = 0; ks < 8; ++ks)
            aq[ks] = *(const bf16x8*)(qrowp + ks * 32 + hi * 8);
    }

    f32x4 o[16];
    const f32x4 zero = {0.f, 0.f, 0.f, 0.f};
#pragma unroll
    for (int n = 0; n < 16; ++n) o[n] = zero;
    float m[4], l[4], tm[4];
#pragma unroll
    for (int r = 0; r < 4; ++r) { m[r] = -1e30f; tm[r] = -1e30f; l[r] = 0.f; }

    for (int t = 0; t < 64; ++t) {
        const long kvg = (long)b * 2048 + t * 32;
        // stage kp tile [32][256] bf16, XOR swizzle ((kv&7)<<4) on the 512B row
#pragma unroll
        for (int c2 = 0; c2 < 4; ++c2) {
            int idx = c2 * 256 + tid;       // 1024 x 16B
            int byt = idx * 16;
            int kv = byt >> 9;
            int inner = byt & 511;
            uint4 v = *(const uint4*)((const char*)(kp + (kvg + kv) * 256) + inner);
            *(uint4*)(kp_lds + (kv << 9) + (inner ^ ((kv & 7) << 4))) = v;
        }
        // stage tsp transposed: tspT[d][kv]
#pragma unroll
        for (int i2 = 0; i2 < 8; ++i2) {
            int idx = i2 * 256 + tid;       // 2048 groups of 4 d-elements
            int d4 = (idx & 63) * 4;
            int kv = idx >> 6;
            bf16x4 v = *(const bf16x4*)(tspb + (kvg + kv) * 256 + d4);
            tspT[d4 + 0][kv] = v[0];
            tspT[d4 + 1][kv] = v[1];
            tspT[d4 + 2][kv] = v[2];
            tspT[d4 + 3][kv] = v[3];
        }
        __syncthreads();

        // S = qp * kp^T  (pre-scaled by 1/temperature via qp)
        f32x4 s[2];
#pragma unroll
        for (int n = 0; n < 2; ++n) {
            s[n] = zero;
            int kv = n * 16 + lo;
#pragma unroll
            for (int ks = 0; ks < 8; ++ks) {
                int byt = (kv << 9) + (((ks * 64) + hi * 16) ^ ((kv & 7) << 4));
                bf16x8 bk = *(const bf16x8*)(kp_lds + byt);
                s[n] = mfma16(aq[ks], bk, s[n]);
            }
        }

        // online softmax (defer-max THR=8); tm tracks true max for the gate
        float pm[4];
#pragma unroll
        for (int r = 0; r < 4; ++r) {
            float v = fmaxf(s[0][r], s[1][r]);
            v = fmaxf(v, __shfl_xor(v, 1));
            v = fmaxf(v, __shfl_xor(v, 2));
            v = fmaxf(v, __shfl_xor(v, 4));
            v = fmaxf(v, __shfl_xor(v, 8));
            pm[r] = v;
            tm[r] = fmaxf(tm[r], v);
        }
        bool grow = false;
#pragma unroll
        for (int r = 0; r < 4; ++r) grow |= (pm[r] > m[r] + 8.f);
        if (__any(grow)) {
#pragma unroll
            for (int r = 0; r < 4; ++r) {
                float nm = fmaxf(m[r], pm[r]);
                float a = __expf(m[r] - nm);
                m[r] = nm;
                l[r] *= a;
#pragma unroll
                for (int n = 0; n < 16; ++n) o[n][r] *= a;
            }
        }
        float pv[2][4];
#pragma unroll
        for (int r = 0; r < 4; ++r) {
            pv[0][r] = __expf(s[0][r] - m[r]);
            pv[1][r] = __expf(s[1][r] - m[r]);
            float su = pv[0][r] + pv[1][r];
            su += __shfl_xor(su, 1);
            su += __shfl_xor(su, 2);
            su += __shfl_xor(su, 4);
            su += __shfl_xor(su, 8);
            l[r] += su;
        }
        // write P (bf16) to per-wave LDS: P[row][kv], row=hi*4+r, kv=n*16+lo
#pragma unroll
        for (int n = 0; n < 2; ++n)
#pragma unroll
            for (int r = 0; r < 4; ++r)
                p_lds[wave][hi * 4 + r][n * 16 + lo] = (bf16)pv[n][r];

        // PV: O += P * tsp   (A=P from p_lds, B=tspT; same k-mapping both sides)
        bf16x8 pa = *(const bf16x8*)((const char*)&p_lds[wave][0][0] + lo * 80 + hi * 16);
#pragma unroll
        for (int dt = 0; dt < 16; ++dt) {
            bf16x8 bt = *(const bf16x8*)((const char*)&tspT[0][0] + (dt * 16 + lo) * 80 + hi * 16);
            o[dt] = mfma16(pa, bt, o[dt]);
        }
        __syncthreads();   // protect kp_lds/tspT before next stage
    }

    // epilogue: gated = (q + O/l) * sigmoid(true_max)
#pragma unroll
    for (int r = 0; r < 4; ++r) {
        float prob = 1.f / (1.f + __expf(-tm[r]));
        float invl = 1.f / l[r];
        long row = qbase_g + wave * 16 + hi * 4 + r;
#pragma unroll
        for (int dt = 0; dt < 16; ++dt) {
            int col = dt * 16 + lo;
            float outv = o[dt][r] * invl;
            float g = (qorig[row * 256 + col] + outv) * prob;
            gated[row * 256 + col] = g;
        }
    }
}

extern "C" void kernel_launch(void* const* d_in, const int* in_sizes, int n_in,
                              void* d_out, int out_size, void* d_ws, size_t ws_size,
                              hipStream_t stream) {
    const float* q    = (const float*)d_in[0];
    const float* k    = (const float*)d_in[1];
    const float* tsp  = (const float*)d_in[2];
    const float* w_qk = (const float*)d_in[3];
    const float* w1   = (const float*)d_in[4];
    const float* b1   = (const float*)d_in[5];
    float* out = (float*)d_out;
    char* ws = (char*)d_ws;

    // ws layout (84,148,224 bytes total)
    bf16*  qp_b  = (bf16*)(ws + 0);
    bf16*  kp_b  = (bf16*)(ws + 16777216);
    bf16*  tspb  = (bf16*)(ws + 33554432);
    float* gated = (float*)(ws + 50331648);
    bf16*  wqkb  = (bf16*)(ws + 83886080);
    bf16*  w1b   = (bf16*)(ws + 84017152);

    convert_f32_bf16<<<64, 256, 0, stream>>>(w_qk, wqkb, 16384);
    convert_f32_bf16<<<64, 256, 0, stream>>>(w1, w1b, 16384);
    convert_f32_bf16<<<8192, 256, 0, stream>>>(tsp, tspb, 2097152);

    // qp = (q @ W^T) / 16 ; kp = k @ W^T   (temperature folded into qp)
    gemm256<true, false><<<512, 256, 0, stream>>>(q, wqkb, nullptr, 0.0625f, qp_b);
    gemm256<true, false><<<512, 256, 0, stream>>>(k, wqkb, nullptr, 1.0f, kp_b);

    dim3 fg(32, 16);
    flash_kernel<<<fg, 256, 0, stream>>>(qp_b, kp_b, tspb, q, gated);

    // out = gated @ w1^T + b1  (f32 output)
    gemm256<false, true><<<512, 256, 0, stream>>>(gated, w1b, b1, 1.0f, out);
}

// Round 2
// 380.464 us; speedup vs baseline: 1.1616x; 1.1616x over previous
//
#include <hip/hip_runtime.h>
#include <hip/hip_bf16.h>

typedef __bf16 bf16;
typedef __bf16 bf16x8 __attribute__((ext_vector_type(8)));
typedef __bf16 bf16x4 __attribute__((ext_vector_type(4)));
typedef float f32x4 __attribute__((ext_vector_type(4)));

static __device__ __forceinline__ f32x4 mfma16(bf16x8 a, bf16x8 b, f32x4 c) {
    return __builtin_amdgcn_mfma_f32_16x16x32_bf16(a, b, c, 0, 0, 0);
}

#define LKV 2048
#define DM 256

// ---------------- convert f32 -> bf16 (vectorized x4) ----------------
__global__ void convert_f32_bf16(const float* __restrict__ src, bf16* __restrict__ dst, int n4) {
    int i = blockIdx.x * blockDim.x + threadIdx.x;
    if (i < n4) {
        float4 v = *(const float4*)(src + (size_t)i * 4);
        bf16x4 o;
        o[0] = (bf16)v.x; o[1] = (bf16)v.y; o[2] = (bf16)v.z; o[3] = (bf16)v.w;
        *(bf16x4*)(dst + (size_t)i * 4) = o;
    }
}

// ---------------- tiled transpose: tsp f32 [B][2048][256] -> tspT bf16 [B][256][2048] ----
// 64x64 tiles, f32 LDS with 65-word rows (odd stride -> conflict-free both phases)
__global__ __launch_bounds__(256) void transpose_tsp(const float* __restrict__ src,
                                                     bf16* __restrict__ dst) {
    __shared__ float tile[64][65];
    const int tid = threadIdx.x;
    const int b = blockIdx.z;
    const int kv0 = blockIdx.x * 64, d0 = blockIdx.y * 64;
#pragma unroll
    for (int i = 0; i < 4; ++i) {
        int idx = i * 256 + tid;
        int kv = idx >> 4, c4 = (idx & 15) * 4;
        float4 v = *(const float4*)(src + ((long)(b * LKV + kv0 + kv)) * DM + d0 + c4);
        tile[kv][c4 + 0] = v.x; tile[kv][c4 + 1] = v.y;
        tile[kv][c4 + 2] = v.z; tile[kv][c4 + 3] = v.w;
    }
    __syncthreads();
#pragma unroll
    for (int i = 0; i < 2; ++i) {
        int idx = i * 256 + tid;
        int d = idx >> 3, kc = idx & 7;
        bf16x8 o;
#pragma unroll
        for (int j = 0; j < 8; ++j) o[j] = (bf16)tile[kc * 8 + j][d];
        *(bf16x8*)(dst + ((long)(b * DM + d0 + d)) * LKV + kv0 + kc * 8) = o;
    }
}

// ---------------- GEMM: Y[M x 256] = X[M x 256] (f32) * W^T (bf16 [256][256]) ----------------
template<bool OUT_BF16, bool HAS_BIAS>
__global__ __launch_bounds__(256) void gemm256(const float* __restrict__ X,
                                               const bf16* __restrict__ W,
                                               const float* __restrict__ bias,
                                               float scale,
                                               void* __restrict__ Y) {
    __shared__ __align__(16) bf16 Xl[64][264];
    __shared__ __align__(16) bf16 Wl[256][40];
    const int tid  = threadIdx.x;
    const int lane = tid & 63, wave = tid >> 6;
    const int hi = lane >> 4, lo = lane & 15;
    const long rowbase = (long)blockIdx.x * 64;

#pragma unroll
    for (int i = 0; i < 16; ++i) {
        int idx4 = i * 256 + tid;
        int e = idx4 * 4;
        int r = e >> 8, c = e & 255;
        float4 v = *(const float4*)(X + (rowbase + r) * 256 + c);
        bf16x4 o;
        o[0] = (bf16)v.x; o[1] = (bf16)v.y; o[2] = (bf16)v.z; o[3] = (bf16)v.w;
        *(bf16x4*)(&Xl[r][c]) = o;
    }

    f32x4 acc[16];
    const f32x4 zero = {0.f, 0.f, 0.f, 0.f};
#pragma unroll
    for (int n = 0; n < 16; ++n) acc[n] = zero;

    for (int ks = 0; ks < 8; ++ks) {
        __syncthreads();
#pragma unroll
        for (int c = 0; c < 4; ++c) {
            int idx = c * 256 + tid;
            int e = idx >> 2, part = idx & 3;
            uint4 v = *(const uint4*)((const char*)W + (size_t)e * 512 + ks * 64 + part * 16);
            *(uint4*)((char*)&Wl[0][0] + e * 80 + part * 16) = v;
        }
        __syncthreads();
        bf16x8 a = *(const bf16x8*)((const char*)&Xl[0][0] + (wave * 16 + lo) * 528 + ks * 64 + hi * 16);
#pragma unroll
        for (int n = 0; n < 16; ++n) {
            bf16x8 bfr = *(const bf16x8*)((const char*)&Wl[0][0] + (n * 16 + lo) * 80 + hi * 16);
            acc[n] = mfma16(a, bfr, acc[n]);
        }
    }

#pragma unroll
    for (int n = 0; n < 16; ++n) {
        int col = n * 16 + lo;
        float bv = HAS_BIAS ? bias[col] : 0.f;
#pragma unroll
        for (int r = 0; r < 4; ++r) {
            long row = rowbase + wave * 16 + hi * 4 + r;
            float v = acc[n][r] * scale + bv;
            if (OUT_BF16) ((bf16*)Y)[row * 256 + col] = (bf16)v;
            else          ((float*)Y)[row * 256 + col] = v;
        }
    }
}

// ---------------- flash attention + gate, v2 ----------------
// grid = 512 (XCD-swizzled -> (batch, qblock)), block = 256 (4 waves x 16 q-rows).
// KV tile = 64.  LDS: kp [64][512B] swz, tspT [256][128B] swz, P [4][16][144B].
__global__ __launch_bounds__(256, 2) void flash2(const bf16* __restrict__ qp,
                                                 const bf16* __restrict__ kp,
                                                 const bf16* __restrict__ tspT,
                                                 const float* __restrict__ qorig,
                                                 float* __restrict__ gated) {
    __shared__ __align__(16) char kp_lds[64 * 512];
    __shared__ __align__(16) char tsp_lds[256 * 128];
    __shared__ __align__(16) char p_lds[4 * 16 * 144];
    const int tid  = threadIdx.x;
    const int lane = tid & 63, wave = tid >> 6;
    const int hi = lane >> 4, lo = lane & 15;

    // XCD-aware swizzle: 512 blocks, 8 XCDs, 64/XCD -> 2 consecutive batches per XCD
    int id  = (int)blockIdx.x;
    int bid = (id & 7) * 64 + (id >> 3);
    const int b  = bid >> 5;
    const int qb = bid & 31;
    const long qbase  = (long)b * LKV + qb * 64;
    const long kvbase = (long)b * LKV;

    // q fragments: 16 rows/wave, full K=256
    bf16x8 aq[8];
    {
        const bf16* qrow = qp + (qbase + wave * 16 + lo) * DM;
#pragma unroll
        for (int ks = 0; ks < 8; ++ks) aq[ks] = *(const bf16x8*)(qrow + ks * 32 + hi * 8);
    }

    bf16x8 ones;
#pragma unroll
    for (int j = 0; j < 8; ++j) ones[j] = (bf16)1.0f;

    f32x4 o[16];
    f32x4 o_l;
    const f32x4 zero = {0.f, 0.f, 0.f, 0.f};
#pragma unroll
    for (int n = 0; n < 16; ++n) o[n] = zero;
    o_l = zero;
    float m[4], tm[4];
#pragma unroll
    for (int r = 0; r < 4; ++r) { m[r] = -1e30f; tm[r] = -1e30f; }

    const char* kp_g  = (const char*)(kp + kvbase * DM);
    const char* tsp_g = (const char*)(tspT + (long)b * DM * LKV);

    uint4 kreg[8], treg[8];

    // ---- stage tile 0 ----
#pragma unroll
    for (int c = 0; c < 8; ++c) {
        int idx = c * 256 + tid;
        int kv = idx >> 5, i16 = idx & 31;
        kreg[c] = *(const uint4*)(kp_g + ((long)kv * DM) * 2 + i16 * 16);
        int d = idx >> 3, kc = idx & 7;
        treg[c] = *(const uint4*)(tsp_g + ((long)d * LKV + kc * 8) * 2);
    }
#pragma unroll
    for (int c = 0; c < 8; ++c) {
        int idx = c * 256 + tid;
        int kv = idx >> 5, i16 = idx & 31;
        *(uint4*)(kp_lds + (kv << 9) + ((i16 * 16) ^ ((kv & 7) << 4))) = kreg[c];
        int d = idx >> 3, kc = idx & 7;
        *(uint4*)(tsp_lds + (d << 7) + ((kc * 16) ^ ((d & 7) << 4))) = treg[c];
    }
    __syncthreads();

    for (int t = 0; t < 32; ++t) {
        // T14: issue next tile's global loads before compute
        if (t < 31) {
            const long koff = (long)(t + 1) * 64;
#pragma unroll
            for (int c = 0; c < 8; ++c) {
                int idx = c * 256 + tid;
                int kv = idx >> 5, i16 = idx & 31;
                kreg[c] = *(const uint4*)(kp_g + ((koff + kv) * DM) * 2 + i16 * 16);
                int d = idx >> 3, kc = idx & 7;
                treg[c] = *(const uint4*)(tsp_g + ((long)d * LKV + koff + kc * 8) * 2);
            }
        }

        // ---- QK^T: S[16q][64kv], pre-scaled via qp ----
        f32x4 s[4];
        __builtin_amdgcn_s_setprio(1);
#pragma unroll
        for (int n = 0; n < 4; ++n) {
            s[n] = zero;
            int kv = n * 16 + lo;
            const char* rowp = kp_lds + (kv << 9);
            int swz = (kv & 7) << 4;
#pragma unroll
            for (int ks = 0; ks < 8; ++ks) {
                bf16x8 bk = *(const bf16x8*)(rowp + ((ks * 64 + hi * 16) ^ swz));
                s[n] = mfma16(aq[ks], bk, s[n]);
            }
        }
        __builtin_amdgcn_s_setprio(0);

        // ---- online softmax: tile max (4 shfl per r), defer-max THR=8 ----
        float pm[4];
#pragma unroll
        for (int r = 0; r < 4; ++r) {
            float v = fmaxf(fmaxf(s[0][r], s[1][r]), fmaxf(s[2][r], s[3][r]));
            v = fmaxf(v, __shfl_xor(v, 1));
            v = fmaxf(v, __shfl_xor(v, 2));
            v = fmaxf(v, __shfl_xor(v, 4));
            v = fmaxf(v, __shfl_xor(v, 8));
            pm[r] = v;
            tm[r] = fmaxf(tm[r], v);
        }
        bool grow = false;
#pragma unroll
        for (int r = 0; r < 4; ++r) grow |= (pm[r] > m[r] + 8.f);
        if (__any(grow)) {
#pragma unroll
            for (int r = 0; r < 4; ++r) {
                float nm = fmaxf(m[r], pm[r]);
                float a = __expf(m[r] - nm);
                m[r] = nm;
                o_l[r] *= a;
#pragma unroll
                for (int n = 0; n < 16; ++n) o[n][r] *= a;
            }
        }

        // ---- P = exp(S - m), write bf16 to per-wave LDS [row=hi*4+r][kv] (144B rows) ----
        char* pw = p_lds + wave * 2304;
#pragma unroll
        for (int n = 0; n < 4; ++n)
#pragma unroll
            for (int r = 0; r < 4; ++r) {
                float p = __expf(s[n][r] - m[r]);
                *(bf16*)(pw + (hi * 4 + r) * 144 + (n * 16 + lo) * 2) = (bf16)p;
            }

        // ---- PV + l via ones-MFMA ----
        bf16x8 pa0 = *(const bf16x8*)(pw + lo * 144 + hi * 16);
        bf16x8 pa1 = *(const bf16x8*)(pw + lo * 144 + 64 + hi * 16);
        o_l = mfma16(pa0, ones, o_l);
        o_l = mfma16(pa1, ones, o_l);
        __builtin_amdgcn_s_setprio(1);
#pragma unroll
        for (int dt = 0; dt < 16; ++dt) {
            int d = dt * 16 + lo;
            const char* trp = tsp_lds + (d << 7);
            int sw = (d & 7) << 4;
            bf16x8 bt0 = *(const bf16x8*)(trp + ((hi * 16) ^ sw));
            o[dt] = mfma16(pa0, bt0, o[dt]);
            bf16x8 bt1 = *(const bf16x8*)(trp + ((64 + hi * 16) ^ sw));
            o[dt] = mfma16(pa1, bt1, o[dt]);
        }
        __builtin_amdgcn_s_setprio(0);

        if (t < 31) {
            __syncthreads();
#pragma unroll
            for (int c = 0; c < 8; ++c) {
                int idx = c * 256 + tid;
                int kv = idx >> 5, i16 = idx & 31;
                *(uint4*)(kp_lds + (kv << 9) + ((i16 * 16) ^ ((kv & 7) << 4))) = kreg[c];
                int d = idx >> 3, kc = idx & 7;
                *(uint4*)(tsp_lds + (d << 7) + ((kc * 16) ^ ((d & 7) << 4))) = treg[c];
            }
            __syncthreads();
        }
    }

    // ---- epilogue: gated = (q + O/l) * sigmoid(true_max) ----
#pragma unroll
    for (int r = 0; r < 4; ++r) {
        float prob = 1.f / (1.f + __expf(-tm[r]));
        float invl = 1.f / o_l[r];
        long row = qbase + wave * 16 + hi * 4 + r;
#pragma unroll
        for (int dt = 0; dt < 16; ++dt) {
            int col = dt * 16 + lo;
            float outv = o[dt][r] * invl;
            float g = (qorig[row * 256 + col] + outv) * prob;
            gated[row * 256 + col] = g;
        }
    }
}

extern "C" void kernel_launch(void* const* d_in, const int* in_sizes, int n_in,
                              void* d_out, int out_size, void* d_ws, size_t ws_size,
                              hipStream_t stream) {
    const float* q    = (const float*)d_in[0];
    const float* k    = (const float*)d_in[1];
    const float* tsp  = (const float*)d_in[2];
    const float* w_qk = (const float*)d_in[3];
    const float* w1   = (const float*)d_in[4];
    const float* b1   = (const float*)d_in[5];
    float* out = (float*)d_out;
    char* ws = (char*)d_ws;

    bf16*  qp_b  = (bf16*)(ws + 0);
    bf16*  kp_b  = (bf16*)(ws + 16777216);
    bf16*  tspT  = (bf16*)(ws + 33554432);
    float* gated = (float*)(ws + 50331648);
    bf16*  wqkb  = (bf16*)(ws + 83886080);
    bf16*  w1b   = (bf16*)(ws + 84017152);

    convert_f32_bf16<<<64, 256, 0, stream>>>(w_qk, wqkb, 16384);
    convert_f32_bf16<<<64, 256, 0, stream>>>(w1, w1b, 16384);

    dim3 tg(32, 4, 16);
    transpose_tsp<<<tg, 256, 0, stream>>>(tsp, tspT);

    gemm256<true, false><<<512, 256, 0, stream>>>(q, wqkb, nullptr, 0.0625f, qp_b);
    gemm256<true, false><<<512, 256, 0, stream>>>(k, wqkb, nullptr, 1.0f, kp_b);

    flash2<<<512, 256, 0, stream>>>(qp_b, kp_b, tspT, q, gated);

    gemm256<false, true><<<512, 256, 0, stream>>>(gated, w1b, b1, 1.0f, out);
}

// Round 3
// 197.595 us; speedup vs baseline: 2.2366x; 1.9255x over previous
//
#include <hip/hip_runtime.h>
#include <hip/hip_bf16.h>

typedef __bf16 bf16;
typedef __bf16 bf16x8 __attribute__((ext_vector_type(8)));
typedef __bf16 bf16x4 __attribute__((ext_vector_type(4)));
typedef float f32x4 __attribute__((ext_vector_type(4)));

static __device__ __forceinline__ f32x4 mfma16(bf16x8 a, bf16x8 b, f32x4 c) {
    return __builtin_amdgcn_mfma_f32_16x16x32_bf16(a, b, c, 0, 0, 0);
}

static __device__ __forceinline__ void load16_to_lds(const void* g, void* l) {
    __builtin_amdgcn_global_load_lds(
        (const __attribute__((address_space(1))) unsigned int*)g,
        (__attribute__((address_space(3))) unsigned int*)l, 16, 0, 0);
}

#define LKV 2048
#define DM 256

// ---------------- convert both weights f32 -> bf16 in one launch ----------------
__global__ void convert_two(const float* __restrict__ a, bf16* __restrict__ da,
                            const float* __restrict__ b, bf16* __restrict__ db) {
    int blk = blockIdx.x;
    const float* src = (blk < 64) ? a : b;
    bf16* dst = (blk < 64) ? da : db;
    int i = (blk & 63) * 256 + threadIdx.x;
    float4 v = *(const float4*)(src + (size_t)i * 4);
    bf16x4 o;
    o[0] = (bf16)v.x; o[1] = (bf16)v.y; o[2] = (bf16)v.z; o[3] = (bf16)v.w;
    *(bf16x4*)(dst + (size_t)i * 4) = o;
}

// ---------------- tiled transpose: tsp f32 [B][2048][256] -> tspT bf16 [B][256][2048] ----
__global__ __launch_bounds__(256) void transpose_tsp(const float* __restrict__ src,
                                                     bf16* __restrict__ dst) {
    __shared__ float tile[64][65];
    const int tid = threadIdx.x;
    const int b = blockIdx.z;
    const int kv0 = blockIdx.x * 64, d0 = blockIdx.y * 64;
#pragma unroll
    for (int i = 0; i < 4; ++i) {
        int idx = i * 256 + tid;
        int kv = idx >> 4, c4 = (idx & 15) * 4;
        float4 v = *(const float4*)(src + ((long)(b * LKV + kv0 + kv)) * DM + d0 + c4);
        tile[kv][c4 + 0] = v.x; tile[kv][c4 + 1] = v.y;
        tile[kv][c4 + 2] = v.z; tile[kv][c4 + 3] = v.w;
    }
    __syncthreads();
#pragma unroll
    for (int i = 0; i < 2; ++i) {
        int idx = i * 256 + tid;
        int d = idx >> 3, kc = idx & 7;
        bf16x8 o;
#pragma unroll
        for (int j = 0; j < 8; ++j) o[j] = (bf16)tile[kc * 8 + j][d];
        *(bf16x8*)(dst + ((long)(b * DM + d0 + d)) * LKV + kv0 + kc * 8) = o;
    }
}

// ---------------- GEMM body: Y[64 x 256] = X[64 x 256] * W^T (bf16 [256][256]) ----------------
template<bool IN_BF16, bool OUT_BF16, bool HAS_BIAS>
static __device__ __forceinline__ void gemm_body(const void* __restrict__ Xv,
                                                 const bf16* __restrict__ W,
                                                 const float* __restrict__ bias,
                                                 float scale, void* __restrict__ Y,
                                                 long rowbase) {
    __shared__ __align__(16) bf16 Xl[64][264];
    __shared__ __align__(16) bf16 Wl[256][40];
    const int tid  = threadIdx.x;
    const int lane = tid & 63, wave = tid >> 6;
    const int hi = lane >> 4, lo = lane & 15;

    if (IN_BF16) {
        const bf16* Xb = (const bf16*)Xv;
#pragma unroll
        for (int i = 0; i < 8; ++i) {
            int idx = i * 256 + tid;
            int r = idx >> 5, c8 = (idx & 31) * 8;
            uint4 v = *(const uint4*)(Xb + (rowbase + r) * 256 + c8);
            *(uint4*)(&Xl[r][c8]) = v;
        }
    } else {
        const float* X = (const float*)Xv;
#pragma unroll
        for (int i = 0; i < 16; ++i) {
            int idx4 = i * 256 + tid;
            int e = idx4 * 4;
            int r = e >> 8, c = e & 255;
            float4 v = *(const float4*)(X + (rowbase + r) * 256 + c);
            bf16x4 o;
            o[0] = (bf16)v.x; o[1] = (bf16)v.y; o[2] = (bf16)v.z; o[3] = (bf16)v.w;
            *(bf16x4*)(&Xl[r][c]) = o;
        }
    }

    f32x4 acc[16];
    const f32x4 zero = {0.f, 0.f, 0.f, 0.f};
#pragma unroll
    for (int n = 0; n < 16; ++n) acc[n] = zero;

    for (int ks = 0; ks < 8; ++ks) {
        __syncthreads();
#pragma unroll
        for (int c = 0; c < 4; ++c) {
            int idx = c * 256 + tid;
            int e = idx >> 2, part = idx & 3;
            uint4 v = *(const uint4*)((const char*)W + (size_t)e * 512 + ks * 64 + part * 16);
            *(uint4*)((char*)&Wl[0][0] + e * 80 + part * 16) = v;
        }
        __syncthreads();
        bf16x8 a = *(const bf16x8*)((const char*)&Xl[0][0] + (wave * 16 + lo) * 528 + ks * 64 + hi * 16);
#pragma unroll
        for (int n = 0; n < 16; ++n) {
            bf16x8 bfr = *(const bf16x8*)((const char*)&Wl[0][0] + (n * 16 + lo) * 80 + hi * 16);
            acc[n] = mfma16(a, bfr, acc[n]);
        }
    }

#pragma unroll
    for (int n = 0; n < 16; ++n) {
        int col = n * 16 + lo;
        float bv = HAS_BIAS ? bias[col] : 0.f;
#pragma unroll
        for (int r = 0; r < 4; ++r) {
            long row = rowbase + wave * 16 + hi * 4 + r;
            float v = acc[n][r] * scale + bv;
            if (OUT_BF16) ((bf16*)Y)[row * 256 + col] = (bf16)v;
            else          ((float*)Y)[row * 256 + col] = v;
        }
    }
}

// combined q & k projection: blocks [0,512) -> qp (scale 1/16), [512,1024) -> kp
__global__ __launch_bounds__(256) void gemm_qk(const float* __restrict__ q,
                                               const float* __restrict__ k,
                                               const bf16* __restrict__ W,
                                               bf16* __restrict__ qp,
                                               bf16* __restrict__ kp) {
    bool is_k = blockIdx.x >= 512;
    const float* X = is_k ? k : q;
    bf16* Y = is_k ? kp : qp;
    float scale = is_k ? 1.0f : 0.0625f;
    long rowbase = (long)(blockIdx.x & 511) * 64;
    gemm_body<false, true, false>(X, W, nullptr, scale, Y, rowbase);
}

__global__ __launch_bounds__(256) void gemm_out(const bf16* __restrict__ gated,
                                                const bf16* __restrict__ W,
                                                const float* __restrict__ bias,
                                                float* __restrict__ out) {
    gemm_body<true, false, true>(gated, W, bias, 1.0f, out, (long)blockIdx.x * 64);
}

// ---------------- flash attention + gate, v3 ----------------
// grid = 512 (XCD-swizzled), block = 256 (4 waves x 16 q-rows). KV tile = 32,
// double-buffered LDS filled by global_load_lds with pre-swizzled sources.
__global__ __launch_bounds__(256, 2) void flash3(const bf16* __restrict__ qp,
                                                 const bf16* __restrict__ kp,
                                                 const bf16* __restrict__ tspT,
                                                 const float* __restrict__ qorig,
                                                 bf16* __restrict__ gated) {
    __shared__ __align__(16) char kp_lds[2][32 * 512];   // [kv][512B], chunk i holds global chunk i^(kv&7)
    __shared__ __align__(16) char tsp_lds[2][256 * 64];  // [d][64B],  chunk c holds global chunk c^((d>>1)&3)
    __shared__ __align__(16) char p_lds[4][16 * 80];     // per-wave P [16 q][32 kv], 80B rows
    const int tid  = threadIdx.x;
    const int lane = tid & 63, wave = tid >> 6;
    const int hi = lane >> 4, lo = lane & 15;

    int id  = (int)blockIdx.x;
    int bid = (id & 7) * 64 + (id >> 3);
    const int b  = bid >> 5;
    const int qb = bid & 31;
    const long qbase = (long)b * LKV + qb * 64;
    const char* kp_g  = (const char*)(kp + (long)b * LKV * DM);
    const char* tsp_g = (const char*)(tspT + (long)b * DM * LKV);

    // per-lane static source offsets (inverse-swizzled) for the 4+4 DMA calls
    int kp_off[4], tsp_off[4];
#pragma unroll
    for (int j = 0; j < 4; ++j) {
        int kv = wave * 8 + j * 2 + (lane >> 5);
        kp_off[j] = kv * 512 + (((lane & 31) ^ (kv & 7)) << 4);
        int d = wave * 64 + j * 16 + (lane >> 2);
        int cp = (lane & 3) ^ ((lane >> 3) & 3);
        tsp_off[j] = d * 4096 + cp * 16;
    }

    // q fragments: 16 rows/wave, full K=256
    bf16x8 aq[8];
    {
        const bf16* qrow = qp + (qbase + wave * 16 + lo) * DM;
#pragma unroll
        for (int ks = 0; ks < 8; ++ks) aq[ks] = *(const bf16x8*)(qrow + ks * 32 + hi * 8);
    }

    bf16x8 ones;
#pragma unroll
    for (int j = 0; j < 8; ++j) ones[j] = (bf16)1.0f;

    f32x4 o[16], o_l;
    const f32x4 zero = {0.f, 0.f, 0.f, 0.f};
#pragma unroll
    for (int n = 0; n < 16; ++n) o[n] = zero;
    o_l = zero;
    float m[4], tm[4];
#pragma unroll
    for (int r = 0; r < 4; ++r) { m[r] = -1e30f; tm[r] = -1e30f; }

    const int kswz = (lo & 7) << 4;          // kp read swizzle (kv&7 == lo&7)
    const int tswz = ((lo >> 1) & 3) << 4;   // tsp read swizzle ((d>>1)&3 == (lo>>1)&3)

    // prologue: stage tile 0 into buf 0
#pragma unroll
    for (int j = 0; j < 4; ++j) {
        load16_to_lds(kp_g + kp_off[j],  &kp_lds[0][wave * 4096 + j * 1024]);
        load16_to_lds(tsp_g + tsp_off[j], &tsp_lds[0][wave * 4096 + j * 1024]);
    }
    __syncthreads();

    for (int t = 0; t < 64; ++t) {
        const int cur = t & 1;
        // issue next tile's DMA into the other buffer (hides under compute)
        if (t < 63) {
            const long ko = (long)(t + 1);
#pragma unroll
            for (int j = 0; j < 4; ++j) {
                load16_to_lds(kp_g + ko * 16384 + kp_off[j],  &kp_lds[cur ^ 1][wave * 4096 + j * 1024]);
                load16_to_lds(tsp_g + ko * 64 + tsp_off[j],   &tsp_lds[cur ^ 1][wave * 4096 + j * 1024]);
            }
        }

        // ---- QK^T: S[16q][32kv] (pre-scaled via qp) ----
        f32x4 s[2];
        __builtin_amdgcn_s_setprio(1);
#pragma unroll
        for (int n = 0; n < 2; ++n) {
            s[n] = zero;
            const char* rowp = &kp_lds[cur][(n * 16 + lo) << 9];
#pragma unroll
            for (int ks = 0; ks < 8; ++ks) {
                bf16x8 bk = *(const bf16x8*)(rowp + ((ks * 64 + hi * 16) ^ kswz));
                s[n] = mfma16(aq[ks], bk, s[n]);
            }
        }
        __builtin_amdgcn_s_setprio(0);

        // ---- online softmax (defer-max THR=8); tm = true max for gate ----
        float pm[4];
#pragma unroll
        for (int r = 0; r < 4; ++r) {
            float v = fmaxf(s[0][r], s[1][r]);
            v = fmaxf(v, __shfl_xor(v, 1));
            v = fmaxf(v, __shfl_xor(v, 2));
            v = fmaxf(v, __shfl_xor(v, 4));
            v = fmaxf(v, __shfl_xor(v, 8));
            pm[r] = v;
            tm[r] = fmaxf(tm[r], v);
        }
        bool grow = false;
#pragma unroll
        for (int r = 0; r < 4; ++r) grow |= (pm[r] > m[r] + 8.f);
        if (__any(grow)) {
#pragma unroll
            for (int r = 0; r < 4; ++r) {
                float nm = fmaxf(m[r], pm[r]);
                float a = __expf(m[r] - nm);
                m[r] = nm;
                o_l[r] *= a;
#pragma unroll
                for (int n = 0; n < 16; ++n) o[n][r] *= a;
            }
        }

        // ---- P = exp(S - m) -> per-wave LDS ----
        char* pw = &p_lds[wave][0];
#pragma unroll
        for (int n = 0; n < 2; ++n)
#pragma unroll
            for (int r = 0; r < 4; ++r) {
                float p = __expf(s[n][r] - m[r]);
                *(bf16*)(pw + (hi * 4 + r) * 80 + (n * 16 + lo) * 2) = (bf16)p;
            }

        // ---- PV + l via ones-MFMA ----
        bf16x8 pa = *(const bf16x8*)(pw + lo * 80 + hi * 16);
        o_l = mfma16(pa, ones, o_l);
        __builtin_amdgcn_s_setprio(1);
#pragma unroll
        for (int dt = 0; dt < 16; ++dt) {
            int d = dt * 16 + lo;
            bf16x8 bt = *(const bf16x8*)(&tsp_lds[cur][d * 64 + ((hi * 16) ^ tswz)]);
            o[dt] = mfma16(pa, bt, o[dt]);
        }
        __builtin_amdgcn_s_setprio(0);

        __syncthreads();   // drains this iter's DMA (vmcnt) + flips buffers safely
    }

    // ---- epilogue: gated = (q + O/l) * sigmoid(true_max), bf16 out ----
#pragma unroll
    for (int r = 0; r < 4; ++r) {
        float prob = 1.f / (1.f + __expf(-tm[r]));
        float invl = 1.f / o_l[r];
        long row = qbase + wave * 16 + hi * 4 + r;
#pragma unroll
        for (int dt = 0; dt < 16; ++dt) {
            int col = dt * 16 + lo;
            float g = (qorig[row * 256 + col] + o[dt][r] * invl) * prob;
            gated[row * 256 + col] = (bf16)g;
        }
    }
}

extern "C" void kernel_launch(void* const* d_in, const int* in_sizes, int n_in,
                              void* d_out, int out_size, void* d_ws, size_t ws_size,
                              hipStream_t stream) {
    const float* q    = (const float*)d_in[0];
    const float* k    = (const float*)d_in[1];
    const float* tsp  = (const float*)d_in[2];
    const float* w_qk = (const float*)d_in[3];
    const float* w1   = (const float*)d_in[4];
    const float* b1   = (const float*)d_in[5];
    float* out = (float*)d_out;
    char* ws = (char*)d_ws;

    bf16* qp_b  = (bf16*)(ws + 0);           // 16 MB
    bf16* kp_b  = (bf16*)(ws + 16777216);    // 16 MB
    bf16* tspT  = (bf16*)(ws + 33554432);    // 16 MB
    bf16* gated = (bf16*)(ws + 50331648);    // 16 MB
    bf16* wqkb  = (bf16*)(ws + 67108864);
    bf16* w1b   = (bf16*)(ws + 67239936);

    convert_two<<<128, 256, 0, stream>>>(w_qk, wqkb, w1, w1b);

    dim3 tg(32, 4, 16);
    transpose_tsp<<<tg, 256, 0, stream>>>(tsp, tspT);

    gemm_qk<<<1024, 256, 0, stream>>>(q, k, wqkb, qp_b, kp_b);

    flash3<<<512, 256, 0, stream>>>(qp_b, kp_b, tspT, q, gated);

    gemm_out<<<512, 256, 0, stream>>>(gated, w1b, b1, out);
}

// Round 4
// 182.919 us; speedup vs baseline: 2.4160x; 1.0802x over previous
//
#include <hip/hip_runtime.h>
#include <hip/hip_bf16.h>

typedef __bf16 bf16;
typedef __bf16 bf16x8 __attribute__((ext_vector_type(8)));
typedef __bf16 bf16x4 __attribute__((ext_vector_type(4)));
typedef __bf16 bf16x2 __attribute__((ext_vector_type(2)));
typedef float f32x4 __attribute__((ext_vector_type(4)));

static __device__ __forceinline__ f32x4 mfma16(bf16x8 a, bf16x8 b, f32x4 c) {
    return __builtin_amdgcn_mfma_f32_16x16x32_bf16(a, b, c, 0, 0, 0);
}

static __device__ __forceinline__ void load16_to_lds(const void* g, void* l) {
    __builtin_amdgcn_global_load_lds(
        (const __attribute__((address_space(1))) unsigned int*)g,
        (__attribute__((address_space(3))) unsigned int*)l, 16, 0, 0);
}

#define LKV 2048
#define DM 256

// ---------------- convert both weights f32 -> bf16 in one launch ----------------
__global__ void convert_two(const float* __restrict__ a, bf16* __restrict__ da,
                            const float* __restrict__ b, bf16* __restrict__ db) {
    int blk = blockIdx.x;
    const float* src = (blk < 64) ? a : b;
    bf16* dst = (blk < 64) ? da : db;
    int i = (blk & 63) * 256 + threadIdx.x;
    float4 v = *(const float4*)(src + (size_t)i * 4);
    bf16x4 o;
    o[0] = (bf16)v.x; o[1] = (bf16)v.y; o[2] = (bf16)v.z; o[3] = (bf16)v.w;
    *(bf16x4*)(dst + (size_t)i * 4) = o;
}

// ---------------- tiled transpose: tsp f32 [B][2048][256] -> tspT bf16 [B][256][2048] ----
__global__ __launch_bounds__(256) void transpose_tsp(const float* __restrict__ src,
                                                     bf16* __restrict__ dst) {
    __shared__ float tile[64][65];
    const int tid = threadIdx.x;
    const int b = blockIdx.z;
    const int kv0 = blockIdx.x * 64, d0 = blockIdx.y * 64;
#pragma unroll
    for (int i = 0; i < 4; ++i) {
        int idx = i * 256 + tid;
        int kv = idx >> 4, c4 = (idx & 15) * 4;
        float4 v = *(const float4*)(src + ((long)(b * LKV + kv0 + kv)) * DM + d0 + c4);
        tile[kv][c4 + 0] = v.x; tile[kv][c4 + 1] = v.y;
        tile[kv][c4 + 2] = v.z; tile[kv][c4 + 3] = v.w;
    }
    __syncthreads();
#pragma unroll
    for (int i = 0; i < 2; ++i) {
        int idx = i * 256 + tid;
        int d = idx >> 3, kc = idx & 7;
        bf16x8 o;
#pragma unroll
        for (int j = 0; j < 8; ++j) o[j] = (bf16)tile[kc * 8 + j][d];
        *(bf16x8*)(dst + ((long)(b * DM + d0 + d)) * LKV + kv0 + kc * 8) = o;
    }
}

// ---------------- GEMM body: Y[64 x 256] = X[64 x 256] * W^T (bf16 [256][256]) ----------------
template<bool IN_BF16, bool OUT_BF16, bool HAS_BIAS>
static __device__ __forceinline__ void gemm_body(const void* __restrict__ Xv,
                                                 const bf16* __restrict__ W,
                                                 const float* __restrict__ bias,
                                                 float scale, void* __restrict__ Y,
                                                 long rowbase) {
    __shared__ __align__(16) bf16 Xl[64][264];
    __shared__ __align__(16) bf16 Wl[256][40];
    const int tid  = threadIdx.x;
    const int lane = tid & 63, wave = tid >> 6;
    const int hi = lane >> 4, lo = lane & 15;

    if (IN_BF16) {
        const bf16* Xb = (const bf16*)Xv;
#pragma unroll
        for (int i = 0; i < 8; ++i) {
            int idx = i * 256 + tid;
            int r = idx >> 5, c8 = (idx & 31) * 8;
            uint4 v = *(const uint4*)(Xb + (rowbase + r) * 256 + c8);
            *(uint4*)(&Xl[r][c8]) = v;
        }
    } else {
        const float* X = (const float*)Xv;
#pragma unroll
        for (int i = 0; i < 16; ++i) {
            int idx4 = i * 256 + tid;
            int e = idx4 * 4;
            int r = e >> 8, c = e & 255;
            float4 v = *(const float4*)(X + (rowbase + r) * 256 + c);
            bf16x4 o;
            o[0] = (bf16)v.x; o[1] = (bf16)v.y; o[2] = (bf16)v.z; o[3] = (bf16)v.w;
            *(bf16x4*)(&Xl[r][c]) = o;
        }
    }

    f32x4 acc[16];
    const f32x4 zero = {0.f, 0.f, 0.f, 0.f};
#pragma unroll
    for (int n = 0; n < 16; ++n) acc[n] = zero;

    for (int ks = 0; ks < 8; ++ks) {
        __syncthreads();
#pragma unroll
        for (int c = 0; c < 4; ++c) {
            int idx = c * 256 + tid;
            int e = idx >> 2, part = idx & 3;
            uint4 v = *(const uint4*)((const char*)W + (size_t)e * 512 + ks * 64 + part * 16);
            *(uint4*)((char*)&Wl[0][0] + e * 80 + part * 16) = v;
        }
        __syncthreads();
        bf16x8 a = *(const bf16x8*)((const char*)&Xl[0][0] + (wave * 16 + lo) * 528 + ks * 64 + hi * 16);
#pragma unroll
        for (int n = 0; n < 16; ++n) {
            bf16x8 bfr = *(const bf16x8*)((const char*)&Wl[0][0] + (n * 16 + lo) * 80 + hi * 16);
            acc[n] = mfma16(a, bfr, acc[n]);
        }
    }

#pragma unroll
    for (int n = 0; n < 16; ++n) {
        int col = n * 16 + lo;
        float bv = HAS_BIAS ? bias[col] : 0.f;
#pragma unroll
        for (int r = 0; r < 4; ++r) {
            long row = rowbase + wave * 16 + hi * 4 + r;
            float v = acc[n][r] * scale + bv;
            if (OUT_BF16) ((bf16*)Y)[row * 256 + col] = (bf16)v;
            else          ((float*)Y)[row * 256 + col] = v;
        }
    }
}

// combined q & k projection: blocks [0,512) -> qp (scale 1/16), [512,1024) -> kp
__global__ __launch_bounds__(256) void gemm_qk(const float* __restrict__ q,
                                               const float* __restrict__ k,
                                               const bf16* __restrict__ W,
                                               bf16* __restrict__ qp,
                                               bf16* __restrict__ kp) {
    bool is_k = blockIdx.x >= 512;
    const float* X = is_k ? k : q;
    bf16* Y = is_k ? kp : qp;
    float scale = is_k ? 1.0f : 0.0625f;
    long rowbase = (long)(blockIdx.x & 511) * 64;
    gemm_body<false, true, false>(X, W, nullptr, scale, Y, rowbase);
}

__global__ __launch_bounds__(256) void gemm_out(const bf16* __restrict__ gated,
                                                const bf16* __restrict__ W,
                                                const float* __restrict__ bias,
                                                float* __restrict__ out) {
    gemm_body<true, false, true>(gated, W, bias, 1.0f, out, (long)blockIdx.x * 64);
}

// ---------------- flash attention + gate, v4: swapped operands, in-register softmax ----
// grid = 512 (XCD-swizzled), block = 256 (4 waves x 16 q-rows, each lane owns q=lane&15).
// KV tile = 32, double-buffered LDS via global_load_lds with pre-swizzled sources.
// S^T = mfma(K,Q): lane holds S[kv = n*16 + 4*hi + r][q = lo].
__global__ __launch_bounds__(256, 2) void flash4(const bf16* __restrict__ qp,
                                                 const bf16* __restrict__ kp,
                                                 const bf16* __restrict__ tspT,
                                                 const float* __restrict__ qorig,
                                                 bf16* __restrict__ gated) {
    __shared__ __align__(16) char kp_lds[2][32 * 512];   // [kv][512B], chunk i holds global chunk i^(kv&7)
    __shared__ __align__(16) char tsp_lds[2][256 * 64];  // [d][64B],  chunk c holds global chunk c^((d>>1)&3)
    const int tid  = threadIdx.x;
    const int lane = tid & 63, wave = tid >> 6;
    const int hi = lane >> 4, lo = lane & 15;

    int id  = (int)blockIdx.x;
    int bid = (id & 7) * 64 + (id >> 3);
    const int b  = bid >> 5;
    const int qb = bid & 31;
    const long qbase = (long)b * LKV + qb * 64;
    const char* kp_g  = (const char*)(kp + (long)b * LKV * DM);
    const char* tsp_g = (const char*)(tspT + (long)b * DM * LKV);

    // per-lane static source offsets (inverse-swizzled) for the 4+4 DMA calls
    int kp_off[4], tsp_off[4];
#pragma unroll
    for (int j = 0; j < 4; ++j) {
        int kv = wave * 8 + j * 2 + (lane >> 5);
        kp_off[j] = kv * 512 + (((lane & 31) ^ (kv & 7)) << 4);
        int d = wave * 64 + j * 16 + (lane >> 2);
        int cp = (lane & 3) ^ ((lane >> 3) & 3);
        tsp_off[j] = d * 4096 + cp * 16;
    }

    // bpermute source addrs: slot k fetches from lane (2*(hi&1)+(k>>1))*16 + lo
    int bp_src[4];
#pragma unroll
    for (int k2 = 0; k2 < 4; ++k2)
        bp_src[k2] = ((((hi & 1) * 2 + (k2 >> 1)) << 4) + lo) << 2;

    // q fragments: lane's q-row is lo; B-frag k = ks*32 + hi*8 + j
    bf16x8 aq[8];
    {
        const bf16* qrow = qp + (qbase + wave * 16 + lo) * DM;
#pragma unroll
        for (int ks = 0; ks < 8; ++ks) aq[ks] = *(const bf16x8*)(qrow + ks * 32 + hi * 8);
    }

    bf16x8 ones;
#pragma unroll
    for (int j = 0; j < 8; ++j) ones[j] = (bf16)1.0f;

    f32x4 o[16], o_l;
    const f32x4 zero = {0.f, 0.f, 0.f, 0.f};
#pragma unroll
    for (int n = 0; n < 16; ++n) o[n] = zero;
    o_l = zero;
    float m = -1e30f, tm = -1e30f;

    const int kswz = (lo & 7) << 4;          // kp read swizzle (row kv: kv&7 == lo&7)
    const int tswz = ((lo >> 1) & 3) << 4;   // tsp read swizzle (row d: (d>>1)&3 == (lo>>1)&3)

    // prologue: stage tile 0 into buf 0
#pragma unroll
    for (int j = 0; j < 4; ++j) {
        load16_to_lds(kp_g + kp_off[j],  &kp_lds[0][wave * 4096 + j * 1024]);
        load16_to_lds(tsp_g + tsp_off[j], &tsp_lds[0][wave * 4096 + j * 1024]);
    }
    __syncthreads();

    for (int t = 0; t < 64; ++t) {
        const int cur = t & 1;
        if (t < 63) {
            const long ko = (long)(t + 1);
#pragma unroll
            for (int j = 0; j < 4; ++j) {
                load16_to_lds(kp_g + ko * 16384 + kp_off[j],  &kp_lds[cur ^ 1][wave * 4096 + j * 1024]);
                load16_to_lds(tsp_g + ko * 64 + tsp_off[j],   &tsp_lds[cur ^ 1][wave * 4096 + j * 1024]);
            }
        }

        // ---- S^T[kv][q] = mfma(K_frag, Q_frag); lane: q=lo, kv = n*16 + 4*hi + r ----
        f32x4 s[2];
        __builtin_amdgcn_s_setprio(1);
#pragma unroll
        for (int n = 0; n < 2; ++n) {
            s[n] = zero;
            const char* rowp = &kp_lds[cur][(n * 16 + lo) << 9];
#pragma unroll
            for (int ks = 0; ks < 8; ++ks) {
                bf16x8 kk = *(const bf16x8*)(rowp + ((ks * 64 + hi * 16) ^ kswz));
                s[n] = mfma16(kk, aq[ks], s[n]);
            }
        }
        __builtin_amdgcn_s_setprio(0);

        // ---- per-lane softmax for q=lo: 8-reg max + 2 shuffles ----
        float pm = fmaxf(fmaxf(fmaxf(s[0][0], s[0][1]), fmaxf(s[0][2], s[0][3])),
                         fmaxf(fmaxf(s[1][0], s[1][1]), fmaxf(s[1][2], s[1][3])));
        pm = fmaxf(pm, __shfl_xor(pm, 16));
        pm = fmaxf(pm, __shfl_xor(pm, 32));
        tm = fmaxf(tm, pm);
        if (__any(pm > m + 8.f)) {       // defer-max THR=8
            float nm = fmaxf(m, pm);
            float a = __expf(m - nm);
            m = nm;
            o_l *= a;
#pragma unroll
            for (int n = 0; n < 16; ++n) o[n] *= a;
        }

        // ---- P = exp(S-m) -> bf16 pairs; redistribute to PV B-frag via bpermute ----
        int cvt[2][2];
#pragma unroll
        for (int n = 0; n < 2; ++n)
#pragma unroll
            for (int c = 0; c < 2; ++c) {
                bf16x2 pr;
                pr[0] = (bf16)__expf(s[n][2 * c]     - m);
                pr[1] = (bf16)__expf(s[n][2 * c + 1] - m);
                cvt[n][c] = __builtin_bit_cast(int, pr);
            }
        int pki[4];
#pragma unroll
        for (int k2 = 0; k2 < 4; ++k2) {
            int a0 = __builtin_amdgcn_ds_bpermute(bp_src[k2], cvt[0][k2 & 1]);
            int a1 = __builtin_amdgcn_ds_bpermute(bp_src[k2], cvt[1][k2 & 1]);
            pki[k2] = (hi < 2) ? a0 : a1;
        }
        int4 pii = make_int4(pki[0], pki[1], pki[2], pki[3]);
        bf16x8 pk = __builtin_bit_cast(bf16x8, pii);   // P[q=lo][kv = 8*hi + j]

        // ---- PV: O^T[d][q] += tspT_frag * P_frag ; l via ones-MFMA ----
        o_l = mfma16(ones, pk, o_l);
        __builtin_amdgcn_s_setprio(1);
#pragma unroll
        for (int dt = 0; dt < 16; ++dt) {
            int d = dt * 16 + lo;
            bf16x8 tt = *(const bf16x8*)(&tsp_lds[cur][d * 64 + ((hi * 16) ^ tswz)]);
            o[dt] = mfma16(tt, pk, o[dt]);
        }
        __builtin_amdgcn_s_setprio(0);

        __syncthreads();   // drains this iter's DMA (vmcnt) + flips buffers safely
    }

    // ---- epilogue: lane owns q-row lo; d = dt*16 + 4*hi + r ----
    float prob = 1.f / (1.f + __expf(-tm));
    float invl = 1.f / o_l[0];
    long row = qbase + wave * 16 + lo;
#pragma unroll
    for (int dt = 0; dt < 16; ++dt) {
        int c0 = dt * 16 + hi * 4;
        float4 qv = *(const float4*)(qorig + row * 256 + c0);
        bf16x4 g;
        g[0] = (bf16)((qv.x + o[dt][0] * invl) * prob);
        g[1] = (bf16)((qv.y + o[dt][1] * invl) * prob);
        g[2] = (bf16)((qv.z + o[dt][2] * invl) * prob);
        g[3] = (bf16)((qv.w + o[dt][3] * invl) * prob);
        *(bf16x4*)(gated + row * 256 + c0) = g;
    }
}

extern "C" void kernel_launch(void* const* d_in, const int* in_sizes, int n_in,
                              void* d_out, int out_size, void* d_ws, size_t ws_size,
                              hipStream_t stream) {
    const float* q    = (const float*)d_in[0];
    const float* k    = (const float*)d_in[1];
    const float* tsp  = (const float*)d_in[2];
    const float* w_qk = (const float*)d_in[3];
    const float* w1   = (const float*)d_in[4];
    const float* b1   = (const float*)d_in[5];
    float* out = (float*)d_out;
    char* ws = (char*)d_ws;

    bf16* qp_b  = (bf16*)(ws + 0);           // 16 MB
    bf16* kp_b  = (bf16*)(ws + 16777216);    // 16 MB
    bf16* tspT  = (bf16*)(ws + 33554432);    // 16 MB
    bf16* gated = (bf16*)(ws + 50331648);    // 16 MB
    bf16* wqkb  = (bf16*)(ws + 67108864);
    bf16* w1b   = (bf16*)(ws + 67239936);

    convert_two<<<128, 256, 0, stream>>>(w_qk, wqkb, w1, w1b);

    dim3 tg(32, 4, 16);
    transpose_tsp<<<tg, 256, 0, stream>>>(tsp, tspT);

    gemm_qk<<<1024, 256, 0, stream>>>(q, k, wqkb, qp_b, kp_b);

    flash4<<<512, 256, 0, stream>>>(qp_b, kp_b, tspT, q, gated);

    gemm_out<<<512, 256, 0, stream>>>(gated, w1b, b1, out);
}

// Round 6
// 168.610 us; speedup vs baseline: 2.6211x; 1.0849x over previous
//
#include <hip/hip_runtime.h>
#include <hip/hip_bf16.h>

typedef __bf16 bf16;
typedef __bf16 bf16x8 __attribute__((ext_vector_type(8)));
typedef __bf16 bf16x4 __attribute__((ext_vector_type(4)));
typedef __bf16 bf16x2 __attribute__((ext_vector_type(2)));
typedef float f32x4 __attribute__((ext_vector_type(4)));

static __device__ __forceinline__ f32x4 mfma16(bf16x8 a, bf16x8 b, f32x4 c) {
    return __builtin_amdgcn_mfma_f32_16x16x32_bf16(a, b, c, 0, 0, 0);
}

static __device__ __forceinline__ void load16_to_lds(const void* g, void* l) {
    __builtin_amdgcn_global_load_lds(
        (const __attribute__((address_space(1))) unsigned int*)g,
        (__attribute__((address_space(3))) unsigned int*)l, 16, 0, 0);
}

#define LKV 2048
#define DM 256

// ---------------- prep: weight converts (blocks 0..127) + tsp transpose (128..2175) ----
__global__ __launch_bounds__(256) void prep(const float* __restrict__ wqk, bf16* __restrict__ wqkb,
                                            const float* __restrict__ w1,  bf16* __restrict__ w1b,
                                            const float* __restrict__ tsp, bf16* __restrict__ tspT) {
    __shared__ float tile[64][65];
    const int tid = threadIdx.x;
    int bid = (int)blockIdx.x;
    if (bid < 128) {
        const float* src = (bid < 64) ? wqk : w1;
        bf16* dst = (bid < 64) ? wqkb : w1b;
        int i = (bid & 63) * 256 + tid;
        float4 v = *(const float4*)(src + (size_t)i * 4);
        bf16x4 o;
        o[0] = (bf16)v.x; o[1] = (bf16)v.y; o[2] = (bf16)v.z; o[3] = (bf16)v.w;
        *(bf16x4*)(dst + (size_t)i * 4) = o;
        return;
    }
    int id = bid - 128;                 // 2048 transpose tiles
    const int b = id >> 7;
    const int kv0 = (id & 31) * 64, d0 = ((id >> 5) & 3) * 64;
#pragma unroll
    for (int i = 0; i < 4; ++i) {
        int idx = i * 256 + tid;
        int kv = idx >> 4, c4 = (idx & 15) * 4;
        float4 v = *(const float4*)(tsp + ((long)(b * LKV + kv0 + kv)) * DM + d0 + c4);
        tile[kv][c4 + 0] = v.x; tile[kv][c4 + 1] = v.y;
        tile[kv][c4 + 2] = v.z; tile[kv][c4 + 3] = v.w;
    }
    __syncthreads();
#pragma unroll
    for (int i = 0; i < 2; ++i) {
        int idx = i * 256 + tid;
        int d = idx >> 3, kc = idx & 7;
        bf16x8 o;
#pragma unroll
        for (int j = 0; j < 8; ++j) o[j] = (bf16)tile[kc * 8 + j][d];
        *(bf16x8*)(tspT + ((long)(b * DM + d0 + d)) * LKV + kv0 + kc * 8) = o;
    }
}

// ---------------- GEMM body: Y[64 x 256] = X[64 x 256] * W^T (bf16 [256][256]) ----------------
template<bool IN_BF16, bool OUT_BF16, bool HAS_BIAS>
static __device__ __forceinline__ void gemm_body(const void* __restrict__ Xv,
                                                 const bf16* __restrict__ W,
                                                 const float* __restrict__ bias,
                                                 float scale, void* __restrict__ Y,
                                                 long rowbase) {
    __shared__ __align__(16) bf16 Xl[64][264];
    __shared__ __align__(16) bf16 Wl[256][40];
    const int tid  = threadIdx.x;
    const int lane = tid & 63, wave = tid >> 6;
    const int hi = lane >> 4, lo = lane & 15;

    if (IN_BF16) {
        const bf16* Xb = (const bf16*)Xv;
#pragma unroll
        for (int i = 0; i < 8; ++i) {
            int idx = i * 256 + tid;
            int r = idx >> 5, c8 = (idx & 31) * 8;
            uint4 v = *(const uint4*)(Xb + (rowbase + r) * 256 + c8);
            *(uint4*)(&Xl[r][c8]) = v;
        }
    } else {
        const float* X = (const float*)Xv;
#pragma unroll
        for (int i = 0; i < 16; ++i) {
            int idx4 = i * 256 + tid;
            int e = idx4 * 4;
            int r = e >> 8, c = e & 255;
            float4 v = *(const float4*)(X + (rowbase + r) * 256 + c);
            bf16x4 o;
            o[0] = (bf16)v.x; o[1] = (bf16)v.y; o[2] = (bf16)v.z; o[3] = (bf16)v.w;
            *(bf16x4*)(&Xl[r][c]) = o;
        }
    }

    f32x4 acc[16];
    const f32x4 zero = {0.f, 0.f, 0.f, 0.f};
#pragma unroll
    for (int n = 0; n < 16; ++n) acc[n] = zero;

    for (int ks = 0; ks < 8; ++ks) {
        __syncthreads();
#pragma unroll
        for (int c = 0; c < 4; ++c) {
            int idx = c * 256 + tid;
            int e = idx >> 2, part = idx & 3;
            uint4 v = *(const uint4*)((const char*)W + (size_t)e * 512 + ks * 64 + part * 16);
            *(uint4*)((char*)&Wl[0][0] + e * 80 + part * 16) = v;
        }
        __syncthreads();
        bf16x8 a = *(const bf16x8*)((const char*)&Xl[0][0] + (wave * 16 + lo) * 528 + ks * 64 + hi * 16);
#pragma unroll
        for (int n = 0; n < 16; ++n) {
            bf16x8 bfr = *(const bf16x8*)((const char*)&Wl[0][0] + (n * 16 + lo) * 80 + hi * 16);
            acc[n] = mfma16(a, bfr, acc[n]);
        }
    }

#pragma unroll
    for (int n = 0; n < 16; ++n) {
        int col = n * 16 + lo;
        float bv = HAS_BIAS ? bias[col] : 0.f;
#pragma unroll
        for (int r = 0; r < 4; ++r) {
            long row = rowbase + wave * 16 + hi * 4 + r;
            float v = acc[n][r] * scale + bv;
            if (OUT_BF16) ((bf16*)Y)[row * 256 + col] = (bf16)v;
            else          ((float*)Y)[row * 256 + col] = v;
        }
    }
}

__global__ __launch_bounds__(256) void gemm_qk(const float* __restrict__ q,
                                               const float* __restrict__ k,
                                               const bf16* __restrict__ W,
                                               bf16* __restrict__ qp,
                                               bf16* __restrict__ kp) {
    bool is_k = blockIdx.x >= 512;
    const float* X = is_k ? k : q;
    bf16* Y = is_k ? kp : qp;
    float scale = is_k ? 1.0f : 0.0625f;
    long rowbase = (long)(blockIdx.x & 511) * 64;
    gemm_body<false, true, false>(X, W, nullptr, scale, Y, rowbase);
}

__global__ __launch_bounds__(256) void gemm_out(const bf16* __restrict__ gated,
                                                const bf16* __restrict__ W,
                                                const float* __restrict__ bias,
                                                float* __restrict__ out) {
    gemm_body<true, false, true>(gated, W, bias, 1.0f, out, (long)blockIdx.x * 64);
}

// ---------------- flash v5: counted-vmcnt phase machine + cross-tile PV pipeline ----
// grid = 512 (XCD-swizzled), block = 256 (4 waves, lane owns q=lane&15).
// KV tile = 32. kp double-buffered, tsp triple-buffered (PV of tile t runs in phase t+1).
// Phase t: vmcnt(8) -> barrier -> QK(t), PV(t-1), softmax(t) -> barrier -> issue DMA(t+2).
__global__ __launch_bounds__(256, 2) void flash5(const bf16* __restrict__ qp,
                                                 const bf16* __restrict__ kp,
                                                 const bf16* __restrict__ tspT,
                                                 const float* __restrict__ qorig,
                                                 bf16* __restrict__ gated) {
    __shared__ __align__(16) char kbuf[2][16384];   // [kv][512B], chunk i ^= (kv&7)
    __shared__ __align__(16) char tbuf[3][16384];   // [d][64B],  chunk c ^= ((d>>1)&3)
    const int tid  = threadIdx.x;
    const int lane = tid & 63, wave = tid >> 6;
    const int hi = lane >> 4, lo = lane & 15;

    int id  = (int)blockIdx.x;
    int bid = (id & 7) * 64 + (id >> 3);
    const int b  = bid >> 5;
    const int qb = bid & 31;
    const long qbase = (long)b * LKV + qb * 64;
    const char* kp_g  = (const char*)(kp + (long)b * LKV * DM);
    const char* tsp_g = (const char*)(tspT + (long)b * DM * LKV);

    // per-lane inverse-swizzled global source offsets for the DMA
    int kp_off[4], tsp_off[4];
#pragma unroll
    for (int j = 0; j < 4; ++j) {
        int kv = wave * 8 + j * 2 + (lane >> 5);
        kp_off[j] = kv * 512 + (((lane & 31) ^ (kv & 7)) << 4);
        int d = wave * 64 + j * 16 + (lane >> 2);
        int cp = (lane & 3) ^ ((lane >> 3) & 3);
        tsp_off[j] = d * 4096 + cp * 16;
    }

    // bpermute source addrs: slot k fetches from lane (2*(hi&1)+(k>>1))*16 + lo
    int bp_src[4];
#pragma unroll
    for (int k2 = 0; k2 < 4; ++k2)
        bp_src[k2] = ((((hi & 1) * 2 + (k2 >> 1)) << 4) + lo) << 2;

    // q fragments: lane's q-row is lo
    bf16x8 aq[8];
    {
        const bf16* qrow = qp + (qbase + wave * 16 + lo) * DM;
#pragma unroll
        for (int ks = 0; ks < 8; ++ks) aq[ks] = *(const bf16x8*)(qrow + ks * 32 + hi * 8);
    }

    bf16x8 ones;
#pragma unroll
    for (int j = 0; j < 8; ++j) ones[j] = (bf16)1.0f;

    f32x4 o[16], o_l;
    const f32x4 zero = {0.f, 0.f, 0.f, 0.f};
#pragma unroll
    for (int n = 0; n < 16; ++n) o[n] = zero;
    o_l = zero;
    float m = -1e30f, tm = -1e30f;
    bf16x8 pk;
#pragma unroll
    for (int j = 0; j < 8; ++j) pk[j] = (bf16)0.0f;

    const int kswz = (lo & 7) << 4;
    const int tswz = ((lo >> 1) & 3) << 4;

    // prologue: stage tiles 0 and 1
#pragma unroll
    for (int j = 0; j < 4; ++j) {
        load16_to_lds(kp_g + kp_off[j],          &kbuf[0][wave * 4096 + j * 1024]);
        load16_to_lds(tsp_g + tsp_off[j],        &tbuf[0][wave * 4096 + j * 1024]);
    }
#pragma unroll
    for (int j = 0; j < 4; ++j) {
        load16_to_lds(kp_g + 16384 + kp_off[j],  &kbuf[1][wave * 4096 + j * 1024]);
        load16_to_lds(tsp_g + 64 + tsp_off[j],   &tbuf[1][wave * 4096 + j * 1024]);
    }

    int ts3 = 2;   // (t+2)%3 == (t-1)%3: PV-read slot and DMA-write slot for this phase
    for (int t = 0; t < 64; ++t) {
        if (t < 63) { asm volatile("s_waitcnt vmcnt(8)" ::: "memory"); }
        else        { asm volatile("s_waitcnt vmcnt(0)" ::: "memory"); }
        __builtin_amdgcn_sched_barrier(0);
        __builtin_amdgcn_s_barrier();
        __builtin_amdgcn_sched_barrier(0);

        // ---- QK(t): S^T[kv][q] = mfma(K,Q); lane: q=lo, kv = n*16 + 4*hi + r ----
        f32x4 s[2];
        const char* kb = kbuf[t & 1];
        __builtin_amdgcn_s_setprio(1);
#pragma unroll
        for (int n = 0; n < 2; ++n) {
            s[n] = zero;
            const char* rowp = kb + ((n * 16 + lo) << 9);
#pragma unroll
            for (int ks = 0; ks < 8; ++ks) {
                bf16x8 kk = *(const bf16x8*)(rowp + ((ks * 64 + hi * 16) ^ kswz));
                s[n] = mfma16(kk, aq[ks], s[n]);
            }
        }
        // ---- PV(t-1): independent of softmax(t); overlaps its latency ----
        if (t > 0) {
            const char* tb = tbuf[ts3];
            o_l = mfma16(ones, pk, o_l);
#pragma unroll
            for (int dt = 0; dt < 16; ++dt) {
                int d = dt * 16 + lo;
                bf16x8 tt = *(const bf16x8*)(tb + d * 64 + ((hi * 16) ^ tswz));
                o[dt] = mfma16(tt, pk, o[dt]);
            }
        }
        __builtin_amdgcn_s_setprio(0);

        // ---- softmax(t) -> pk (consumed next phase) ----
        float pm = fmaxf(fmaxf(fmaxf(s[0][0], s[0][1]), fmaxf(s[0][2], s[0][3])),
                         fmaxf(fmaxf(s[1][0], s[1][1]), fmaxf(s[1][2], s[1][3])));
        pm = fmaxf(pm, __shfl_xor(pm, 16));
        pm = fmaxf(pm, __shfl_xor(pm, 32));
        tm = fmaxf(tm, pm);
        if (__any(pm > m + 8.f)) {       // defer-max THR=8
            float nm = fmaxf(m, pm);
            float a = __expf(m - nm);
            m = nm;
            o_l *= a;
#pragma unroll
            for (int n = 0; n < 16; ++n) o[n] *= a;
        }
        int cvt[2][2];
#pragma unroll
        for (int n = 0; n < 2; ++n)
#pragma unroll
            for (int c = 0; c < 2; ++c) {
                bf16x2 pr;
                pr[0] = (bf16)__expf(s[n][2 * c]     - m);
                pr[1] = (bf16)__expf(s[n][2 * c + 1] - m);
                cvt[n][c] = __builtin_bit_cast(int, pr);
            }
        int pki[4];
#pragma unroll
        for (int k2 = 0; k2 < 4; ++k2) {
            int a0 = __builtin_amdgcn_ds_bpermute(bp_src[k2], cvt[0][k2 & 1]);
            int a1 = __builtin_amdgcn_ds_bpermute(bp_src[k2], cvt[1][k2 & 1]);
            pki[k2] = (hi < 2) ? a0 : a1;
        }
        int4 pii = make_int4(pki[0], pki[1], pki[2], pki[3]);
        pk = __builtin_bit_cast(bf16x8, pii);   // P[q=lo][kv = 8*hi + j]

        __builtin_amdgcn_sched_barrier(0);
        __builtin_amdgcn_s_barrier();
        __builtin_amdgcn_sched_barrier(0);

        // ---- issue DMA(t+2): kp slot t&1 (just read), tsp slot ts3 (just PV-read) ----
        if (t < 62) {
            const long tile = (long)(t + 2);
#pragma unroll
            for (int j = 0; j < 4; ++j) {
                load16_to_lds(kp_g + tile * 16384 + kp_off[j], &kbuf[t & 1][wave * 4096 + j * 1024]);
                load16_to_lds(tsp_g + tile * 64 + tsp_off[j],  &tbuf[ts3][wave * 4096 + j * 1024]);
            }
        }
        ts3 = (ts3 == 2) ? 0 : ts3 + 1;
    }

    // ---- tail: PV(63), slot ts3 (== 0) ----
    {
        const char* tb = tbuf[ts3];
        o_l = mfma16(ones, pk, o_l);
#pragma unroll
        for (int dt = 0; dt < 16; ++dt) {
            int d = dt * 16 + lo;
            bf16x8 tt = *(const bf16x8*)(tb + d * 64 + ((hi * 16) ^ tswz));
            o[dt] = mfma16(tt, pk, o[dt]);
        }
    }

    // ---- epilogue: lane owns q-row lo; d = dt*16 + 4*hi + r ----
    float prob = 1.f / (1.f + __expf(-tm));
    float invl = 1.f / o_l[0];
    long row = qbase + wave * 16 + lo;
#pragma unroll
    for (int dt = 0; dt < 16; ++dt) {
        int c0 = dt * 16 + hi * 4;
        float4 qv = *(const float4*)(qorig + row * 256 + c0);
        bf16x4 g;
        g[0] = (bf16)((qv.x + o[dt][0] * invl) * prob);
        g[1] = (bf16)((qv.y + o[dt][1] * invl) * prob);
        g[2] = (bf16)((qv.z + o[dt][2] * invl) * prob);
        g[3] = (bf16)((qv.w + o[dt][3] * invl) * prob);
        *(bf16x4*)(gated + row * 256 + c0) = g;
    }
}

extern "C" void kernel_launch(void* const* d_in, const int* in_sizes, int n_in,
                              void* d_out, int out_size, void* d_ws, size_t ws_size,
                              hipStream_t stream) {
    const float* q    = (const float*)d_in[0];
    const float* k    = (const float*)d_in[1];
    const float* tsp  = (const float*)d_in[2];
    const float* w_qk = (const float*)d_in[3];
    const float* w1   = (const float*)d_in[4];
    const float* b1   = (const float*)d_in[5];
    float* out = (float*)d_out;
    char* ws = (char*)d_ws;

    bf16* qp_b  = (bf16*)(ws + 0);           // 16 MB
    bf16* kp_b  = (bf16*)(ws + 16777216);    // 16 MB
    bf16* tspT  = (bf16*)(ws + 33554432);    // 16 MB
    bf16* gated = (bf16*)(ws + 50331648);    // 16 MB
    bf16* wqkb  = (bf16*)(ws + 67108864);
    bf16* w1b   = (bf16*)(ws + 67239936);

    prep<<<2176, 256, 0, stream>>>(w_qk, wqkb, w1, w1b, tsp, tspT);

    gemm_qk<<<1024, 256, 0, stream>>>(q, k, wqkb, qp_b, kp_b);

    flash5<<<512, 256, 0, stream>>>(qp_b, kp_b, tspT, q, gated);

    gemm_out<<<512, 256, 0, stream>>>(gated, w1b, b1, out);
}